// Round 2
// baseline (703.469 us; speedup 1.0000x reference)
//
#include <hip/hip_runtime.h>

// Problem constants
#define P_TOTAL 132096
#define NPOOL   4096
#define GDIM    1000
#define HDIM    150
#define MGRP    2048
#define KMAX    128

typedef __attribute__((ext_vector_type(4))) float f32x4;
typedef __attribute__((ext_vector_type(8))) short short8;

// ---------- workspace layout (bytes) ----------
#define OFF_W1CT   0
#define OFF_W1ABT  327680
#define OFF_W2T    983040
#define OFF_ABPRE  1034240
#define OFF_TABS   6277120
#define OFF_SGRID  6289920

__device__ __forceinline__ short f2bf(float f) {
  union { float f; unsigned u; } v; v.f = f;
  unsigned r = v.u + 0x7FFFu + ((v.u >> 16) & 1u);   // RNE
  return (short)(r >> 16);
}

// truncating bf16 pack: one v_perm_b32 per 2 floats
__device__ __forceinline__ short8 pack8t(f32x4 a, f32x4 b) {
  union { f32x4 f; unsigned u[4]; } ua, ub; ua.f = a; ub.f = b;
  union { short8 s; unsigned u[4]; } r;
  r.u[0] = __builtin_amdgcn_perm(ua.u[1], ua.u[0], 0x07060302u);
  r.u[1] = __builtin_amdgcn_perm(ua.u[3], ua.u[2], 0x07060302u);
  r.u[2] = __builtin_amdgcn_perm(ub.u[1], ub.u[0], 0x07060302u);
  r.u[3] = __builtin_amdgcn_perm(ub.u[3], ub.u[2], 0x07060302u);
  return r.s;
}

// ---------- kernel 1: pack weights to bf16, transposed-chunked [c][n][kk] ----------
__global__ __launch_bounds__(256) void pack_kernel(const float* __restrict__ W1,
                                                   const float* __restrict__ W2,
                                                   short* __restrict__ w1ct,
                                                   short* __restrict__ w1abt,
                                                   short* __restrict__ w2t) {
  int idx = blockIdx.x * 256 + threadIdx.x;
  const int T1 = 32*160*32, T2 = 32*320*32, T3 = 5*160*32;
  if (idx < T1) {                               // W1c rows 2000..2999 -> [32][160][32]
    int c = idx / (160*32); int rem = idx % (160*32);
    int n = rem / 32, kk = rem % 32;
    int k = c*32 + kk;
    float v = (k < GDIM && n < HDIM) ? W1[(2000 + k)*HDIM + n] : 0.f;
    w1ct[idx] = f2bf(v);
  } else if (idx < T1 + T2) {                   // [W1a | W1b] -> [32][320][32]
    int i = idx - T1;
    int c = i / (320*32); int rem = i % (320*32);
    int n = rem / 32, kk = rem % 32;
    int k = c*32 + kk;
    float v = 0.f;
    if (k < GDIM) {
      if (n < HDIM)                 v = W1[k*HDIM + n];
      else if (n >= 160 && n < 310) v = W1[(1000 + k)*HDIM + (n - 160)];
    }
    w1abt[i] = f2bf(v);
  } else if (idx < T1 + T2 + T3) {              // W2 -> [5][160][32]
    int i = idx - T1 - T2;
    int c = i / (160*32); int rem = i % (160*32);
    int n = rem / 32, kk = rem % 32;
    int k = c*32 + kk;
    float v = (k < HDIM && n < HDIM) ? W2[k*HDIM + n] : 0.f;
    w2t[i] = f2bf(v);
  }
}

// ---------- kernel 2: phi projection tables (b1 folded into dist table) ----------
__global__ __launch_bounds__(256) void tables_kernel(const float* __restrict__ dist_emb,
                                                     const float* __restrict__ genre_emb,
                                                     const float* __restrict__ spk_emb,
                                                     const float* __restrict__ W1,
                                                     const float* __restrict__ b1,
                                                     float* __restrict__ tabs) {
  int idx = blockIdx.x * 256 + threadIdx.x;     // 20 rows x 160 cols
  if (idx >= 20*160) return;
  int row = idx / 160, n = idx % 160;
  float acc = 0.f;
  if (n < HDIM) {
    const float* emb; int woff;
    if (row < 9)       { emb = dist_emb  + row*20;      woff = 3000; acc = b1[n]; }
    else if (row < 17) { emb = genre_emb + (row-9)*20;  woff = 3020; }
    else               { emb = spk_emb   + (row-17)*20; woff = 3040; }
    #pragma unroll
    for (int kk = 0; kk < 20; ++kk) acc += emb[kk] * W1[(woff + kk)*HDIM + n];
  }
  tabs[idx] = acc;
}

// ---------- kernel 3: ABpre[4096][320] = g_i @ [W1a | W1b]  (bf16 MFMA) ----------
__global__ __launch_bounds__(256) void pre_gemm_kernel(const float* __restrict__ g_i,
                                                       const short* __restrict__ w1abt,
                                                       float* __restrict__ abpre) {
  int wave = threadIdx.x >> 6, lane = threadIdx.x & 63;
  int quad = lane >> 4, n16 = lane & 15;
  int rowbase = blockIdx.x * 64 + wave * 16;
  int colbase = blockIdx.y * 160;

  f32x4 acc[10];
  #pragma unroll
  for (int t = 0; t < 10; ++t) acc[t] = (f32x4){0.f, 0.f, 0.f, 0.f};

  const float* arow = g_i + (long)(rowbase + n16) * GDIM;

  for (int c = 0; c < 32; ++c) {
    int k = c*32 + quad*8;
    short8 a;
    if (k < GDIM) {
      f32x4 x0 = *(const f32x4*)(arow + k);
      f32x4 x1 = *(const f32x4*)(arow + k + 4);
      a = pack8t(x0, x1);
    } else {
      a = (short8){0,0,0,0,0,0,0,0};
    }
    const short* bp = w1abt + ((c*320 + colbase + n16) * 32 + quad*8);
    #pragma unroll
    for (int t = 0; t < 10; ++t) {
      short8 b = *(const short8*)(bp + t*16*32);
      acc[t] = __builtin_amdgcn_mfma_f32_16x16x32_bf16(a, b, acc[t], 0, 0, 0);
    }
  }
  #pragma unroll
  for (int t = 0; t < 10; ++t) {
    #pragma unroll
    for (int r = 0; r < 4; ++r) {
      int row = rowbase + quad*4 + r;
      abpre[(long)row * 320 + colbase + t*16 + n16] = acc[t][r];
    }
  }
}

// ---------- kernel 4: per-pair fused MLP + score scatter ----------
// wave = 32 pairs (2 row-tiles of 16) x 160 cols; block = 4 waves = 128 pairs
__global__ __launch_bounds__(256, 2) void pair_kernel(
    const float* __restrict__ g_i, const float* __restrict__ ms,
    const short* __restrict__ w1ct, const short* __restrict__ w2t,
    const float* __restrict__ abpre, const float* __restrict__ tabs,
    const float* __restrict__ b2, const float* __restrict__ W3,
    const float* __restrict__ b3,
    const int* __restrict__ mention_ids, const int* __restrict__ antecedent_ids,
    const int* __restrict__ dist_ids, const int* __restrict__ genre_ids,
    const int* __restrict__ spk_ids, const int* __restrict__ seg_ids,
    const int* __restrict__ offs, float* __restrict__ sgrid) {

  __shared__ __align__(16) short h1s[4][32*176];   // stride 176 (16B-aligned rows)

  int wave = threadIdx.x >> 6, lane = threadIdx.x & 63;
  int quad = lane >> 4, n16 = lane & 15;
  int p0 = blockIdx.x * 128 + wave * 32;

  // A-fragment rows for this lane: tile0 pair = p0+n16, tile1 pair = p0+16+n16
  int pm0 = p0 + n16, pm1 = p0 + 16 + n16;
  const float* rm0 = g_i + (long)mention_ids[pm0]    * GDIM;
  const float* ra0 = g_i + (long)antecedent_ids[pm0] * GDIM;
  const float* rm1 = g_i + (long)mention_ids[pm1]    * GDIM;
  const float* ra1 = g_i + (long)antecedent_ids[pm1] * GDIM;

  f32x4 acc[2][10];
  #pragma unroll
  for (int t = 0; t < 10; ++t) {
    acc[0][t] = (f32x4){0.f, 0.f, 0.f, 0.f};
    acc[1][t] = (f32x4){0.f, 0.f, 0.f, 0.f};
  }

  // depth-2 prefetched A buffers
  f32x4 bufA[2][8];
  auto loadA = [&](int c, f32x4* dst) {
    int k = c*32 + quad*8;
    if (k < GDIM) {
      dst[0] = *(const f32x4*)(rm0 + k); dst[1] = *(const f32x4*)(rm0 + k + 4);
      dst[2] = *(const f32x4*)(ra0 + k); dst[3] = *(const f32x4*)(ra0 + k + 4);
      dst[4] = *(const f32x4*)(rm1 + k); dst[5] = *(const f32x4*)(rm1 + k + 4);
      dst[6] = *(const f32x4*)(ra1 + k); dst[7] = *(const f32x4*)(ra1 + k + 4);
    } else {
      #pragma unroll
      for (int i = 0; i < 8; ++i) dst[i] = (f32x4){0.f, 0.f, 0.f, 0.f};
    }
  };
  loadA(0, bufA[0]);
  loadA(1, bufA[1]);

  // ---- layer-1 product-term GEMM: [32 x 1024] x [1024 x 160] ----
  for (int c = 0; c < 32; ++c) {
    f32x4* cur = bufA[c & 1];
    short8 af0 = pack8t(cur[0] * cur[2], cur[1] * cur[3]);
    short8 af1 = pack8t(cur[4] * cur[6], cur[5] * cur[7]);
    if (c + 2 < 32) loadA(c + 2, bufA[c & 1]);
    const short* bp = w1ct + ((c*160 + n16) * 32 + quad*8);
    #pragma unroll
    for (int t = 0; t < 10; ++t) {
      short8 b = *(const short8*)(bp + t*16*32);
      acc[0][t] = __builtin_amdgcn_mfma_f32_16x16x32_bf16(af0, b, acc[0][t], 0, 0, 0);
      acc[1][t] = __builtin_amdgcn_mfma_f32_16x16x32_bf16(af1, b, acc[1][t], 0, 0, 0);
    }
  }

  // ---- epilogue 1: add precomputed terms, relu, stash h1 (bf16) in LDS ----
  int idm[2][4], ida[2][4], idd[2][4], idg[2][4], idsp[2][4];
  #pragma unroll
  for (int tile = 0; tile < 2; ++tile) {
    #pragma unroll
    for (int r = 0; r < 4; ++r) {
      int pr = p0 + tile*16 + quad*4 + r;
      idm[tile][r]  = mention_ids[pr];
      ida[tile][r]  = antecedent_ids[pr];
      idd[tile][r]  = dist_ids[pr];
      idg[tile][r]  = genre_ids[pr];
      idsp[tile][r] = spk_ids[pr];
    }
  }
  const float* Dd = tabs;             // 9 x 160 (includes b1)
  const float* Ge = tabs + 9*160;     // 8 x 160
  const float* Se = tabs + 17*160;    // 3 x 160

  #pragma unroll
  for (int tile = 0; tile < 2; ++tile) {
    #pragma unroll
    for (int t = 0; t < 10; ++t) {
      int n = t*16 + n16;
      #pragma unroll
      for (int r = 0; r < 4; ++r) {
        float v = acc[tile][t][r]
                + abpre[(long)idm[tile][r]*320 + n]
                + abpre[(long)ida[tile][r]*320 + 160 + n]
                + Dd[idd[tile][r]*160 + n]
                + Ge[idg[tile][r]*160 + n]
                + Se[idsp[tile][r]*160 + n];
        v = fmaxf(v, 0.f);
        h1s[wave][(tile*16 + quad*4 + r)*176 + n] = f2bf(v);
      }
    }
  }
  __syncthreads();

  // ---- layer 2 + 3 per tile ----
  float bias3 = b3[0];
  float w3v[10], b2v[10];
  #pragma unroll
  for (int t = 0; t < 10; ++t) {
    int n = t*16 + n16;
    w3v[t] = (n < HDIM) ? W3[n] : 0.f;
    b2v[t] = (n < HDIM) ? b2[n] : 0.f;
  }

  #pragma unroll
  for (int tile = 0; tile < 2; ++tile) {
    f32x4 acc2[10];
    #pragma unroll
    for (int t = 0; t < 10; ++t) acc2[t] = (f32x4){0.f, 0.f, 0.f, 0.f};

    #pragma unroll
    for (int c = 0; c < 5; ++c) {
      short8 a = *(const short8*)(&h1s[wave][(tile*16 + n16)*176 + c*32 + quad*8]);
      const short* bp = w2t + ((c*160 + n16) * 32 + quad*8);
      #pragma unroll
      for (int t = 0; t < 10; ++t) {
        short8 b = *(const short8*)(bp + t*16*32);
        acc2[t] = __builtin_amdgcn_mfma_f32_16x16x32_bf16(a, b, acc2[t], 0, 0, 0);
      }
    }

    float part[4] = {0.f, 0.f, 0.f, 0.f};
    #pragma unroll
    for (int t = 0; t < 10; ++t) {
      #pragma unroll
      for (int r = 0; r < 4; ++r) {
        float h2 = fmaxf(acc2[t][r] + b2v[t], 0.f);
        part[r] += h2 * w3v[t];
      }
    }
    for (int msk = 1; msk < 16; msk <<= 1) {
      #pragma unroll
      for (int r = 0; r < 4; ++r) part[r] += __shfl_xor(part[r], msk);
    }

    if (n16 == 0) {
      #pragma unroll
      for (int r = 0; r < 4; ++r) {
        int pr = p0 + tile*16 + quad*4 + r;
        float sc = part[r] + bias3 + ms[idm[tile][r]] + ms[ida[tile][r]];
        sgrid[seg_ids[pr] * KMAX + offs[pr]] = sc;
      }
    }
  }
}

// ---------- kernel 5: per-group softmax (+epsilon) and full output fill ----------
__global__ __launch_bounds__(128) void softmax_kernel(const float* __restrict__ sgrid,
                                                      const int* __restrict__ lengths,
                                                      float* __restrict__ out) {
  int b = blockIdx.x, t = threadIdx.x;   // 128 threads
  if (b == 0) {
    out[t] = (t == 0) ? 1.0f : 1000.0f;
    if (t == 0) out[128] = 1000.0f;
    return;
  }
  int m = b - 1;
  int len = lengths[m];
  float s = (t < len) ? sgrid[m * KMAX + t] : -1e30f;

  __shared__ float redA[2];
  __shared__ float redB[2];

  float v = s;
  #pragma unroll
  for (int o = 32; o >= 1; o >>= 1) v = fmaxf(v, __shfl_xor(v, o));
  if ((t & 63) == 0) redA[t >> 6] = v;
  __syncthreads();
  float mx = fmaxf(fmaxf(redA[0], redA[1]), 0.0f);

  float e = (t < len) ? expf(s - mx) : 0.f;
  float sum = e;
  #pragma unroll
  for (int o = 32; o >= 1; o >>= 1) sum += __shfl_xor(sum, o);
  if ((t & 63) == 0) redB[t >> 6] = sum;
  __syncthreads();

  float eps_e = expf(-mx);
  float denom = redB[0] + redB[1] + eps_e;

  float* row = out + (long)(m + 1) * 129;
  float val;
  if (t < len)       val = e / denom;
  else if (t == len) val = eps_e / denom;
  else               val = 1000.0f;
  row[t] = val;
  if (t == 0) row[128] = (len == KMAX) ? (eps_e / denom) : 1000.0f;
}

extern "C" void kernel_launch(void* const* d_in, const int* in_sizes, int n_in,
                              void* d_out, int out_size, void* d_ws, size_t ws_size,
                              hipStream_t stream) {
  const float* g_i        = (const float*)d_in[0];
  const float* ms         = (const float*)d_in[1];
  const float* dist_emb   = (const float*)d_in[2];
  const float* genre_emb  = (const float*)d_in[3];
  const float* spk_emb    = (const float*)d_in[4];
  const float* W1         = (const float*)d_in[5];
  const float* b1         = (const float*)d_in[6];
  const float* W2         = (const float*)d_in[7];
  const float* b2         = (const float*)d_in[8];
  const float* W3         = (const float*)d_in[9];
  const float* b3         = (const float*)d_in[10];
  const int* mention_ids    = (const int*)d_in[11];
  const int* antecedent_ids = (const int*)d_in[12];
  const int* dist_ids       = (const int*)d_in[13];
  const int* genre_ids      = (const int*)d_in[14];
  const int* spk_ids        = (const int*)d_in[15];
  const int* lengths        = (const int*)d_in[16];
  const int* seg_ids        = (const int*)d_in[17];
  const int* offsets        = (const int*)d_in[18];

  char* ws = (char*)d_ws;
  short* w1ct  = (short*)(ws + OFF_W1CT);
  short* w1abt = (short*)(ws + OFF_W1ABT);
  short* w2t   = (short*)(ws + OFF_W2T);
  float* abpre = (float*)(ws + OFF_ABPRE);
  float* tabs  = (float*)(ws + OFF_TABS);
  float* sgrid = (float*)(ws + OFF_SGRID);

  const int packN = 32*160*32 + 32*320*32 + 5*160*32;
  pack_kernel<<<(packN + 255)/256, 256, 0, stream>>>(W1, W2, w1ct, w1abt, w2t);
  tables_kernel<<<(20*160 + 255)/256, 256, 0, stream>>>(dist_emb, genre_emb, spk_emb, W1, b1, tabs);
  dim3 gpre(NPOOL/64, 2);
  pre_gemm_kernel<<<gpre, 256, 0, stream>>>(g_i, w1abt, abpre);
  pair_kernel<<<P_TOTAL/128, 256, 0, stream>>>(g_i, ms, w1ct, w2t, abpre, tabs,
                                               b2, W3, b3,
                                               mention_ids, antecedent_ids,
                                               dist_ids, genre_ids, spk_ids,
                                               seg_ids, offsets, sgrid);
  softmax_kernel<<<MGRP + 1, 128, 0, stream>>>(sgrid, lengths, (float*)d_out);
}

// Round 3
// 377.913 us; speedup vs baseline: 1.8615x; 1.8615x over previous
//
#include <hip/hip_runtime.h>

// Problem constants
#define P_TOTAL 132096
#define NPOOL   4096
#define GDIM    1000
#define HDIM    150
#define MGRP    2048
#define KMAX    128

typedef __attribute__((ext_vector_type(4))) float f32x4;
typedef __attribute__((ext_vector_type(8))) short short8;
typedef __attribute__((ext_vector_type(4))) unsigned int u32x4;

// ---------- workspace layout (bytes) ----------
// W1cT : bf16 [32][160][32]          327,680 @ 0
// W1abT: bf16 [32][320][32]          655,360 @ 327,680
// W2T  : bf16 [5][160][32]            51,200 @ 983,040
// ABpre: f32  [4096][320]          5,242,880 @ 1,034,240
// tabs : f32  [20][160]               12,800 @ 6,277,120
// sgrid: f32  [2048][128]          1,048,576 @ 6,289,920
// gbf  : bf16 [4096][1024]         8,388,608 @ 7,338,496   (zero-padded cols 1000..1023)
// total: 15,727,104 B
#define OFF_W1CT   0
#define OFF_W1ABT  327680
#define OFF_W2T    983040
#define OFF_ABPRE  1034240
#define OFF_TABS   6277120
#define OFF_SGRID  6289920
#define OFF_GBF    7338496

__device__ __forceinline__ short f2bf(float f) {
  union { float f; unsigned u; } v; v.f = f;
  unsigned r = v.u + 0x7FFFu + ((v.u >> 16) & 1u);   // RNE
  return (short)(r >> 16);
}

// bf16 product of 8 packed bf16 pairs -> packed bf16 (truncating)
__device__ __forceinline__ short8 bfmul8(u32x4 m, u32x4 a) {
  union { short8 s; unsigned u[4]; } r;
  #pragma unroll
  for (int i = 0; i < 4; ++i) {
    float ml = __builtin_bit_cast(float, m[i] << 16);
    float mh = __builtin_bit_cast(float, m[i] & 0xFFFF0000u);
    float al = __builtin_bit_cast(float, a[i] << 16);
    float ah = __builtin_bit_cast(float, a[i] & 0xFFFF0000u);
    unsigned pl = __builtin_bit_cast(unsigned, ml * al);
    unsigned ph = __builtin_bit_cast(unsigned, mh * ah);
    r.u[i] = __builtin_amdgcn_perm(ph, pl, 0x07060302u);
  }
  return r.s;
}

// ---------- kernel 1: pack weights to bf16, transposed-chunked [c][n][kk] ----------
__global__ __launch_bounds__(256) void pack_kernel(const float* __restrict__ W1,
                                                   const float* __restrict__ W2,
                                                   short* __restrict__ w1ct,
                                                   short* __restrict__ w1abt,
                                                   short* __restrict__ w2t) {
  int idx = blockIdx.x * 256 + threadIdx.x;
  const int T1 = 32*160*32, T2 = 32*320*32, T3 = 5*160*32;
  if (idx < T1) {                               // W1c rows 2000..2999 -> [32][160][32]
    int c = idx / (160*32); int rem = idx % (160*32);
    int n = rem / 32, kk = rem % 32;
    int k = c*32 + kk;
    float v = (k < GDIM && n < HDIM) ? W1[(2000 + k)*HDIM + n] : 0.f;
    w1ct[idx] = f2bf(v);
  } else if (idx < T1 + T2) {                   // [W1a | W1b] -> [32][320][32]
    int i = idx - T1;
    int c = i / (320*32); int rem = i % (320*32);
    int n = rem / 32, kk = rem % 32;
    int k = c*32 + kk;
    float v = 0.f;
    if (k < GDIM) {
      if (n < HDIM)                 v = W1[k*HDIM + n];
      else if (n >= 160 && n < 310) v = W1[(1000 + k)*HDIM + (n - 160)];
    }
    w1abt[i] = f2bf(v);
  } else if (idx < T1 + T2 + T3) {              // W2 -> [5][160][32]
    int i = idx - T1 - T2;
    int c = i / (160*32); int rem = i % (160*32);
    int n = rem / 32, kk = rem % 32;
    int k = c*32 + kk;
    float v = (k < HDIM && n < HDIM) ? W2[k*HDIM + n] : 0.f;
    w2t[i] = f2bf(v);
  }
}

// ---------- kernel 1b: g_i -> bf16, zero-padded to 1024 cols ----------
__global__ __launch_bounds__(256) void g2bf_kernel(const float* __restrict__ g_i,
                                                   unsigned* __restrict__ gbf) {
  int idx = blockIdx.x * 256 + threadIdx.x;     // one dword = 2 cols
  if (idx >= NPOOL * 512) return;
  int row = idx >> 9, jd = idx & 511;
  int c0 = jd * 2;
  unsigned lo = 0, hi = 0;
  if (c0 < GDIM)     lo = (unsigned)(unsigned short)f2bf(g_i[row*GDIM + c0]);
  if (c0 + 1 < GDIM) hi = (unsigned)(unsigned short)f2bf(g_i[row*GDIM + c0 + 1]);
  gbf[idx] = lo | (hi << 16);
}

// ---------- kernel 2: phi projection tables (b1 folded into dist table) ----------
__global__ __launch_bounds__(256) void tables_kernel(const float* __restrict__ dist_emb,
                                                     const float* __restrict__ genre_emb,
                                                     const float* __restrict__ spk_emb,
                                                     const float* __restrict__ W1,
                                                     const float* __restrict__ b1,
                                                     float* __restrict__ tabs) {
  int idx = blockIdx.x * 256 + threadIdx.x;     // 20 rows x 160 cols
  if (idx >= 20*160) return;
  int row = idx / 160, n = idx % 160;
  float acc = 0.f;
  if (n < HDIM) {
    const float* emb; int woff;
    if (row < 9)       { emb = dist_emb  + row*20;      woff = 3000; acc = b1[n]; }
    else if (row < 17) { emb = genre_emb + (row-9)*20;  woff = 3020; }
    else               { emb = spk_emb   + (row-17)*20; woff = 3040; }
    #pragma unroll
    for (int kk = 0; kk < 20; ++kk) acc += emb[kk] * W1[(woff + kk)*HDIM + n];
  }
  tabs[idx] = acc;
}

// ---------- kernel 3: ABpre[4096][320] = g_i @ [W1a | W1b]  (bf16 MFMA) ----------
__global__ __launch_bounds__(256) void pre_gemm_kernel(const unsigned short* __restrict__ gbf,
                                                       const short* __restrict__ w1abt,
                                                       float* __restrict__ abpre) {
  int wave = threadIdx.x >> 6, lane = threadIdx.x & 63;
  int quad = lane >> 4, n16 = lane & 15;
  int rowbase = blockIdx.x * 64 + wave * 16;
  int colbase = blockIdx.y * 160;

  f32x4 acc[10];
  #pragma unroll
  for (int t = 0; t < 10; ++t) acc[t] = (f32x4){0.f, 0.f, 0.f, 0.f};

  const unsigned short* arow = gbf + (long)(rowbase + n16) * 1024 + quad*8;

  for (int c = 0; c < 32; ++c) {
    short8 a = *(const short8*)(arow + c*32);
    const short* bp = w1abt + ((c*320 + colbase + n16) * 32 + quad*8);
    #pragma unroll
    for (int t = 0; t < 10; ++t) {
      short8 b = *(const short8*)(bp + t*16*32);
      acc[t] = __builtin_amdgcn_mfma_f32_16x16x32_bf16(a, b, acc[t], 0, 0, 0);
    }
  }
  #pragma unroll
  for (int t = 0; t < 10; ++t) {
    #pragma unroll
    for (int r = 0; r < 4; ++r) {
      int row = rowbase + quad*4 + r;
      abpre[(long)row * 320 + colbase + t*16 + n16] = acc[t][r];
    }
  }
}

// ---------- kernel 4: per-pair fused MLP + score scatter ----------
// wave = 32 pairs (2 row-tiles of 16) x 160 cols; block = 4 waves = 128 pairs
__global__ __launch_bounds__(256) void pair_kernel(
    const unsigned short* __restrict__ gbf, const float* __restrict__ ms,
    const short* __restrict__ w1ct, const short* __restrict__ w2t,
    const float* __restrict__ abpre, const float* __restrict__ tabs,
    const float* __restrict__ b2, const float* __restrict__ W3,
    const float* __restrict__ b3,
    const int* __restrict__ mention_ids, const int* __restrict__ antecedent_ids,
    const int* __restrict__ dist_ids, const int* __restrict__ genre_ids,
    const int* __restrict__ spk_ids, const int* __restrict__ seg_ids,
    const int* __restrict__ offs, float* __restrict__ sgrid) {

  __shared__ __align__(16) short h1s[4][32*184];   // stride 184 -> 2-way-free b128 reads

  int wave = threadIdx.x >> 6, lane = threadIdx.x & 63;
  int quad = lane >> 4, n16 = lane & 15;
  int p0 = blockIdx.x * 128 + wave * 32;

  // per-lane A row pointers (bf16 rows, one cacheline per 32-elem chunk slice)
  int pm0 = p0 + n16, pm1 = p0 + 16 + n16;
  const unsigned short* pm0p = gbf + (long)mention_ids[pm0]    * 1024 + quad*8;
  const unsigned short* pa0p = gbf + (long)antecedent_ids[pm0] * 1024 + quad*8;
  const unsigned short* pm1p = gbf + (long)mention_ids[pm1]    * 1024 + quad*8;
  const unsigned short* pa1p = gbf + (long)antecedent_ids[pm1] * 1024 + quad*8;

  f32x4 acc0[10], acc1[10];
  #pragma unroll
  for (int t = 0; t < 10; ++t) {
    acc0[t] = (f32x4){0.f, 0.f, 0.f, 0.f};
    acc1[t] = (f32x4){0.f, 0.f, 0.f, 0.f};
  }

  // named-register pipeline (NO indexed buffers -> no scratch)
  u32x4 M0 = *(const u32x4*)(pm0p);
  u32x4 A0 = *(const u32x4*)(pa0p);
  u32x4 M1 = *(const u32x4*)(pm1p);
  u32x4 A1 = *(const u32x4*)(pa1p);

  for (int c = 0; c < 32; ++c) {
    short8 f0 = bfmul8(M0, A0);
    short8 f1 = bfmul8(M1, A1);
    if (c < 31) {
      M0 = *(const u32x4*)(pm0p + (c+1)*32);
      A0 = *(const u32x4*)(pa0p + (c+1)*32);
      M1 = *(const u32x4*)(pm1p + (c+1)*32);
      A1 = *(const u32x4*)(pa1p + (c+1)*32);
    }
    const short* bp = w1ct + ((c*160 + n16) * 32 + quad*8);
    #pragma unroll
    for (int t = 0; t < 10; ++t) {
      short8 b = *(const short8*)(bp + t*16*32);
      acc0[t] = __builtin_amdgcn_mfma_f32_16x16x32_bf16(f0, b, acc0[t], 0, 0, 0);
      acc1[t] = __builtin_amdgcn_mfma_f32_16x16x32_bf16(f1, b, acc1[t], 0, 0, 0);
    }
  }

  // ---- epilogue 1: add precomputed terms, relu, stash h1 (bf16) in LDS ----
  int idm0[4], ida0[4], idm1[4], ida1[4];
  int idd0[4], idg0[4], ids0[4], idd1[4], idg1[4], ids1[4];
  #pragma unroll
  for (int r = 0; r < 4; ++r) {
    int pr0 = p0 + quad*4 + r;
    int pr1 = p0 + 16 + quad*4 + r;
    idm0[r] = mention_ids[pr0];    idm1[r] = mention_ids[pr1];
    ida0[r] = antecedent_ids[pr0]; ida1[r] = antecedent_ids[pr1];
    idd0[r] = dist_ids[pr0];       idd1[r] = dist_ids[pr1];
    idg0[r] = genre_ids[pr0];      idg1[r] = genre_ids[pr1];
    ids0[r] = spk_ids[pr0];        ids1[r] = spk_ids[pr1];
  }
  const float* Dd = tabs;             // 9 x 160 (includes b1)
  const float* Ge = tabs + 9*160;     // 8 x 160
  const float* Se = tabs + 17*160;    // 3 x 160

  #pragma unroll
  for (int t = 0; t < 10; ++t) {
    int n = t*16 + n16;
    #pragma unroll
    for (int r = 0; r < 4; ++r) {
      float v0 = acc0[t][r]
               + abpre[(long)idm0[r]*320 + n]
               + abpre[(long)ida0[r]*320 + 160 + n]
               + Dd[idd0[r]*160 + n] + Ge[idg0[r]*160 + n] + Se[ids0[r]*160 + n];
      float v1 = acc1[t][r]
               + abpre[(long)idm1[r]*320 + n]
               + abpre[(long)ida1[r]*320 + 160 + n]
               + Dd[idd1[r]*160 + n] + Ge[idg1[r]*160 + n] + Se[ids1[r]*160 + n];
      h1s[wave][(quad*4 + r)*184 + n]        = f2bf(fmaxf(v0, 0.f));
      h1s[wave][(16 + quad*4 + r)*184 + n]   = f2bf(fmaxf(v1, 0.f));
    }
  }
  // h1s slice is wave-private: no __syncthreads needed (lgkmcnt handled by compiler)

  // ---- layer 2 + 3 per tile ----
  float bias3 = b3[0];
  float w3v[10], b2v[10];
  #pragma unroll
  for (int t = 0; t < 10; ++t) {
    int n = t*16 + n16;
    w3v[t] = (n < HDIM) ? W3[n] : 0.f;
    b2v[t] = (n < HDIM) ? b2[n] : 0.f;
  }

  #pragma unroll
  for (int tile = 0; tile < 2; ++tile) {
    f32x4 acc2[10];
    #pragma unroll
    for (int t = 0; t < 10; ++t) acc2[t] = (f32x4){0.f, 0.f, 0.f, 0.f};

    #pragma unroll
    for (int c = 0; c < 5; ++c) {
      short8 a = *(const short8*)(&h1s[wave][(tile*16 + n16)*184 + c*32 + quad*8]);
      const short* bp = w2t + ((c*160 + n16) * 32 + quad*8);
      #pragma unroll
      for (int t = 0; t < 10; ++t) {
        short8 b = *(const short8*)(bp + t*16*32);
        acc2[t] = __builtin_amdgcn_mfma_f32_16x16x32_bf16(a, b, acc2[t], 0, 0, 0);
      }
    }

    float part[4] = {0.f, 0.f, 0.f, 0.f};
    #pragma unroll
    for (int t = 0; t < 10; ++t) {
      #pragma unroll
      for (int r = 0; r < 4; ++r) {
        float h2 = fmaxf(acc2[t][r] + b2v[t], 0.f);
        part[r] += h2 * w3v[t];
      }
    }
    for (int msk = 1; msk < 16; msk <<= 1) {
      #pragma unroll
      for (int r = 0; r < 4; ++r) part[r] += __shfl_xor(part[r], msk);
    }

    if (n16 == 0) {
      #pragma unroll
      for (int r = 0; r < 4; ++r) {
        int pr = p0 + tile*16 + quad*4 + r;
        int im = tile ? idm1[r] : idm0[r];
        int ia = tile ? ida1[r] : ida0[r];
        float sc = part[r] + bias3 + ms[im] + ms[ia];
        sgrid[seg_ids[pr] * KMAX + offs[pr]] = sc;
      }
    }
  }
}

// ---------- kernel 5: per-group softmax (+epsilon) and full output fill ----------
__global__ __launch_bounds__(128) void softmax_kernel(const float* __restrict__ sgrid,
                                                      const int* __restrict__ lengths,
                                                      float* __restrict__ out) {
  int b = blockIdx.x, t = threadIdx.x;   // 128 threads
  if (b == 0) {
    out[t] = (t == 0) ? 1.0f : 1000.0f;
    if (t == 0) out[128] = 1000.0f;
    return;
  }
  int m = b - 1;
  int len = lengths[m];
  float s = (t < len) ? sgrid[m * KMAX + t] : -1e30f;

  __shared__ float redA[2];
  __shared__ float redB[2];

  float v = s;
  #pragma unroll
  for (int o = 32; o >= 1; o >>= 1) v = fmaxf(v, __shfl_xor(v, o));
  if ((t & 63) == 0) redA[t >> 6] = v;
  __syncthreads();
  float mx = fmaxf(fmaxf(redA[0], redA[1]), 0.0f);

  float e = (t < len) ? expf(s - mx) : 0.f;
  float sum = e;
  #pragma unroll
  for (int o = 32; o >= 1; o >>= 1) sum += __shfl_xor(sum, o);
  if ((t & 63) == 0) redB[t >> 6] = sum;
  __syncthreads();

  float eps_e = expf(-mx);
  float denom = redB[0] + redB[1] + eps_e;

  float* row = out + (long)(m + 1) * 129;
  float val;
  if (t < len)       val = e / denom;
  else if (t == len) val = eps_e / denom;
  else               val = 1000.0f;
  row[t] = val;
  if (t == 0) row[128] = (len == KMAX) ? (eps_e / denom) : 1000.0f;
}

extern "C" void kernel_launch(void* const* d_in, const int* in_sizes, int n_in,
                              void* d_out, int out_size, void* d_ws, size_t ws_size,
                              hipStream_t stream) {
  const float* g_i        = (const float*)d_in[0];
  const float* ms         = (const float*)d_in[1];
  const float* dist_emb   = (const float*)d_in[2];
  const float* genre_emb  = (const float*)d_in[3];
  const float* spk_emb    = (const float*)d_in[4];
  const float* W1         = (const float*)d_in[5];
  const float* b1         = (const float*)d_in[6];
  const float* W2         = (const float*)d_in[7];
  const float* b2         = (const float*)d_in[8];
  const float* W3         = (const float*)d_in[9];
  const float* b3         = (const float*)d_in[10];
  const int* mention_ids    = (const int*)d_in[11];
  const int* antecedent_ids = (const int*)d_in[12];
  const int* dist_ids       = (const int*)d_in[13];
  const int* genre_ids      = (const int*)d_in[14];
  const int* spk_ids        = (const int*)d_in[15];
  const int* lengths        = (const int*)d_in[16];
  const int* seg_ids        = (const int*)d_in[17];
  const int* offsets        = (const int*)d_in[18];

  char* ws = (char*)d_ws;
  short* w1ct  = (short*)(ws + OFF_W1CT);
  short* w1abt = (short*)(ws + OFF_W1ABT);
  short* w2t   = (short*)(ws + OFF_W2T);
  float* abpre = (float*)(ws + OFF_ABPRE);
  float* tabs  = (float*)(ws + OFF_TABS);
  float* sgrid = (float*)(ws + OFF_SGRID);
  unsigned short* gbf = (unsigned short*)(ws + OFF_GBF);

  const int packN = 32*160*32 + 32*320*32 + 5*160*32;
  pack_kernel<<<(packN + 255)/256, 256, 0, stream>>>(W1, W2, w1ct, w1abt, w2t);
  g2bf_kernel<<<(NPOOL*512 + 255)/256, 256, 0, stream>>>(g_i, (unsigned*)gbf);
  tables_kernel<<<(20*160 + 255)/256, 256, 0, stream>>>(dist_emb, genre_emb, spk_emb, W1, b1, tabs);
  dim3 gpre(NPOOL/64, 2);
  pre_gemm_kernel<<<gpre, 256, 0, stream>>>(gbf, w1abt, abpre);
  pair_kernel<<<P_TOTAL/128, 256, 0, stream>>>(gbf, ms, w1ct, w2t, abpre, tabs,
                                               b2, W3, b3,
                                               mention_ids, antecedent_ids,
                                               dist_ids, genre_ids, spk_ids,
                                               seg_ids, offsets, sgrid);
  softmax_kernel<<<MGRP + 1, 128, 0, stream>>>(sgrid, lengths, (float*)d_out);
}